// Round 1
// baseline (3016.600 us; speedup 1.0000x reference)
//
#include <hip/hip_runtime.h>
#include <math.h>

// ConvGRU v9: ONE persistent cooperative kernel for all 64 timesteps.
// Same per-step math as v8 (MFMA implicit-GEMM, parity-split LDS copies,
// K-split x2 over 8 waves), but:
//  - grid 64x4 = 256 blocks = 1 block/CU, co-resident via cooperative launch
//  - per-(b,y) flag counters (agent-scope atomics + fences) implement a
//    neighbor-only wavefront sync: block (y,b) at step t waits for blocks
//    (y-1,y,y+1,b) to finish step t-1.  No grid-wide barrier, no launches.
//  - wfrag staged into LDS once (73.7 KB; total LDS 132.6 KB <= 160 KB)
//  - x granules (flag-independent) are loaded to regs and ds-written BEFORE
//    the flag wait; only h staging sits behind the flag.
// h ping-pongs d_out <-> d_ws; t=63 (odd) writes d_out.
// Cross-XCD visibility: epilogue -> release fence (L2 writeback) -> flag add;
// consumer: relaxed spin -> acquire fence (L2 invalidate) -> h loads.

typedef _Float16 half8 __attribute__((ext_vector_type(8)));
typedef float floatx16 __attribute__((ext_vector_type(16)));

#define RS 144                       // bytes per staged k-row (both copies)
#define CP1 (144 * RS)               // copy1 byte base (20736)
#define SCRDW (2 * 144 * RS / 4)     // scratch dword base (10368)
#define LDS_DW (SCRDW + 4 * 16 * 68) // + 4 tiles x 16 regs x 68-stride (14720 dw)

static __device__ __forceinline__ unsigned pack2(float a, float b) {
    _Float16 ha = (_Float16)a, hb = (_Float16)b;
    unsigned short ua = *(unsigned short*)&ha, ub = *(unsigned short*)&hb;
    return (unsigned)ua | ((unsigned)ub << 16);
}

// ---- pre-kernel: weights -> A-fragment layout (R6-verified, unchanged) ----
__global__ __launch_bounds__(64) void build_wfrag(
    const float* __restrict__ Wx, const float* __restrict__ Wh,
    uint4* __restrict__ wfrag)
{
    const int bid   = blockIdx.x;            // 0..71
    const int mtile = bid / 36, chunk = bid % 36;
    const int lane  = threadIdx.x;
    const int m     = lane & 31;
    const int grow  = (m < 16) ? (mtile * 16 + m) : (64 + mtile * 16 + (m - 16));
    unsigned short h[8];
    for (int j = 0; j < 8; ++j) {
        int k   = chunk * 16 + (lane >> 5) * 8 + j;
        int cin = k / 12, t12 = k - cin * 12;
        int p = t12 >> 1, o = t12 & 1;
        int ky = p >> 1, q = p & 1;
        int kx = q ? (2 + o) : o;            // q=1,o=1 -> phantom (w=0)
        float w = 0.0f;
        if (!(q && o)) {
            if (cin < 16) w = Wx[((size_t)grow * 16 + cin) * 9 + ky * 3 + kx];
            else          w = Wh[((size_t)grow * 32 + (cin - 16)) * 9 + ky * 3 + kx];
        }
        _Float16 hw = (_Float16)w;
        h[j] = *(unsigned short*)&hw;
    }
    uint4 o4;
    o4.x = (unsigned)h[0] | ((unsigned)h[1] << 16);
    o4.y = (unsigned)h[2] | ((unsigned)h[3] << 16);
    o4.z = (unsigned)h[4] | ((unsigned)h[5] << 16);
    o4.w = (unsigned)h[6] | ((unsigned)h[7] << 16);
    wfrag[(size_t)bid * 64 + lane] = o4;
}

__global__ __launch_bounds__(512, 2) void convgru_persist(
    const float* __restrict__ x, const float* __restrict__ bx,
    const uint4* __restrict__ wfrag,
    float* __restrict__ hO,      // d_out  (hsrc when t even, hdst when t odd)
    float* __restrict__ hW,      // ws     (hdst when t even)
    int* __restrict__ flags)     // [4][64] completion counters (4 per step)
{
    __shared__ unsigned plds[LDS_DW];        // staging + scratch (58,880 B)
    __shared__ uint4    wlds[72 * 64];       // A-fragments      (73,728 B)

    const int tx = threadIdx.x;
    const int y  = blockIdx.x;               // image row 0..63
    const int b  = blockIdx.y;               // batch 0..3
    const int lane  = tx & 63;
    const int wv    = tx >> 6;               // 0..7
    const int kh    = wv & 1;                // k-half: chunks 0-17 / 18-35
    const int mtile = (wv >> 1) & 1;
    const int ntile = wv >> 2;
    const int tile  = wv >> 1;               // 0..3 (shared by kh pair)
    const int xpx   = ntile * 32 + (lane & 31);
    const int half  = lane >> 5;
    const int lb_off = ((xpx & 1) ? (2 * xpx + 6) : (CP1 + 2 * xpx))
                       + half * (2 * RS);
    const char* lbase = (const char*)plds + lb_off;

    // one-time setup: wfrag -> LDS (9 x 512 = 4608 uint4); copy0 halo dword = 0
    #pragma unroll
    for (int i = 0; i < 9; ++i) wlds[i * 512 + tx] = wfrag[i * 512 + tx];
    if (tx < 144) plds[tx * 36 + 34] = 0u;
    // (first in-loop __syncthreads orders these vs first MFMA reads)

    int* const myflag = flags + b * 64 + y;

    #pragma unroll 1
    for (int t = 0; t < 64; ++t) {
        const float* hsrc = (t & 1) ? hW : hO;
        float*       hdst = (t & 1) ? hO : hW;

        // ---- (A) flag-independent prefetch: x granules + own-row hprev ----
        float4 xv0 = make_float4(0.f, 0.f, 0.f, 0.f), xv1 = xv0;
        {
            const int rr = tx >> 4, g = tx & 15;       // tasks 0..511 (cin<16)
            const int cin = rr / 3, ky = rr - cin * 3, ys = y + ky - 1;
            if ((unsigned)ys < 64u)
                xv0 = *(const float4*)(x + (((size_t)(b * 16 + cin) * 64 + t) * 4096)
                                         + ys * 64 + g * 4);
        }
        if (tx < 256) {
            const int task = 512 + tx;                 // tasks 512..767
            const int rr = task >> 4, g = task & 15;
            const int cin = rr / 3, ky = rr - cin * 3, ys = y + ky - 1;
            if ((unsigned)ys < 64u)
                xv1 = *(const float4*)(x + (((size_t)(b * 16 + cin) * 64 + t) * 4096)
                                         + ys * 64 + g * 4);
        }
        float hprev[8];
        if (kh == 0) {                                 // own row y: self-produced
            #pragma unroll
            for (int r = 0; r < 8; ++r) {
                const int row = (r & 3) + 8 * (r >> 2) + 4 * half;
                const int oc  = mtile * 16 + row;
                hprev[r] = hsrc[(size_t)(b * 32 + oc) * 4096 + y * 64 + xpx];
            }
        }

        // ---- (D) x -> LDS (B-area is free: all MFMA reads of step t-1
        //      happened before the previous reduce-sync barrier) ----
        {
            const int rr = tx >> 4, g = tx & 15;
            float prev = __shfl_up(xv0.w, 1);
            if (g == 0) prev = 0.f;
            const int r36 = rr * 36;
            plds[r36 + 2 * g + 2] = pack2(xv0.x, xv0.y);
            plds[r36 + 2 * g + 3] = pack2(xv0.z, xv0.w);
            plds[CP1 / 4 + r36 + 2 * g]     = pack2(prev, xv0.x);
            plds[CP1 / 4 + r36 + 2 * g + 1] = pack2(xv0.y, xv0.z);
            if (g == 15) plds[CP1 / 4 + r36 + 32] = pack2(xv0.w, 0.f);
        }
        if (tx < 256) {                                // waves 0-3 fully active
            const int task = 512 + tx;
            const int rr = task >> 4, g = task & 15;
            float prev = __shfl_up(xv1.w, 1);
            if (g == 0) prev = 0.f;
            const int r36 = rr * 36;
            plds[r36 + 2 * g + 2] = pack2(xv1.x, xv1.y);
            plds[r36 + 2 * g + 3] = pack2(xv1.z, xv1.w);
            plds[CP1 / 4 + r36 + 2 * g]     = pack2(prev, xv1.x);
            plds[CP1 / 4 + r36 + 2 * g + 1] = pack2(xv1.y, xv1.z);
            if (g == 15) plds[CP1 / 4 + r36 + 32] = pack2(xv1.w, 0.f);
        }

        // ---- (B) wait for neighbors' h(t-1); per-wave spin, acquire fence ----
        if (t > 0) {
            if (lane < 3) {
                const int yy = y + (int)lane - 1;
                if (0 <= yy && yy < 64) {
                    const int tgt = 4 * t;             // 4 kh0-waves per step
                    while (__hip_atomic_load(flags + b * 64 + yy, __ATOMIC_RELAXED,
                                             __HIP_MEMORY_SCOPE_AGENT) < tgt) { }
                }
            }
            __builtin_amdgcn_fence(__ATOMIC_ACQUIRE, "agent");
        }

        // ---- (C) h(t-1) -> LDS: tasks 768..2303 (cin 16..47) ----
        #pragma unroll
        for (int j = 0; j < 3; ++j) {
            const int task = 768 + j * 512 + tx;
            const int rr = task >> 4, g = task & 15;
            const int cin = rr / 3, ky = rr - cin * 3, ys = y + ky - 1;
            float4 v = make_float4(0.f, 0.f, 0.f, 0.f);
            if ((unsigned)ys < 64u)
                v = *(const float4*)(hsrc + ((size_t)(b * 32 + (cin - 16)) * 4096)
                                          + ys * 64 + g * 4);
            float prev = __shfl_up(v.w, 1);
            if (g == 0) prev = 0.f;
            const int r36 = rr * 36;
            plds[r36 + 2 * g + 2] = pack2(v.x, v.y);
            plds[r36 + 2 * g + 3] = pack2(v.z, v.w);
            plds[CP1 / 4 + r36 + 2 * g]     = pack2(prev, v.x);
            plds[CP1 / 4 + r36 + 2 * g + 1] = pack2(v.y, v.z);
            if (g == 15) plds[CP1 / 4 + r36 + 32] = pack2(v.w, 0.f);
        }
        __syncthreads();                               // stage-sync

        // ---- MFMA main loop (A-frags from LDS now) ----
        floatx16 acc;
        #pragma unroll
        for (int i = 0; i < 16; ++i) acc[i] = 0.0f;
        const int c0 = kh * 18;
        #pragma unroll
        for (int j = 0; j < 18; ++j) {
            const int c = c0 + j;
            uint4 aw = wlds[(mtile * 36 + c) * 64 + lane];
            const int B0 = c * 4 * RS;
            unsigned d0 = *(const unsigned*)(lbase + B0);
            unsigned d1 = *(const unsigned*)(lbase + B0 + 4);
            unsigned e0 = *(const unsigned*)(lbase + B0 + RS);
            unsigned e1 = *(const unsigned*)(lbase + B0 + RS + 4);
            uint4 bf; bf.x = d0; bf.y = d1; bf.z = e0; bf.w = e1;
            union { uint4 u; half8 h; } ua, ub;
            ua.u = aw; ub.u = bf;
            acc = __builtin_amdgcn_mfma_f32_32x32x16_f16(ua.h, ub.h, acc, 0, 0, 0);
        }

        // ---- K-split reduction ----
        if (kh == 1) {
            #pragma unroll
            for (int r = 0; r < 16; ++r)
                plds[SCRDW + tile * 1088 + r * 68 + lane] = __float_as_uint(acc[r]);
        }
        __syncthreads();                               // reduce-sync

        if (kh == 0) {
            #pragma unroll
            for (int r = 0; r < 16; ++r)
                acc[r] += __uint_as_float(plds[SCRDW + tile * 1088 + r * 68 + lane]);

            // epilogue: gates + h update, write h(t)
            #pragma unroll
            for (int r = 0; r < 8; ++r) {
                const int row = (r & 3) + 8 * (r >> 2) + 4 * half;
                const int oc  = mtile * 16 + row;
                const size_t a = (size_t)(b * 32 + oc) * 4096 + y * 64 + xpx;
                float zp = acc[r]     + bx[oc];
                float np = acc[r + 8] + bx[64 + oc];
                float z  = 1.0f / (1.0f + __expf(-zp));
                float e  = __expf(2.0f * np);
                float n  = 1.0f - 2.0f / (e + 1.0f);               // tanh
                hdst[a] = (1.0f - z) * hprev[r] + z * n;
            }
            // release: drain stores + L2 writeback, then signal
            __builtin_amdgcn_fence(__ATOMIC_RELEASE, "agent");
            if (lane == 0)
                __hip_atomic_fetch_add(myflag, 1, __ATOMIC_RELAXED,
                                       __HIP_MEMORY_SCOPE_AGENT);
        }
    }
}

extern "C" void kernel_launch(void* const* d_in, const int* in_sizes, int n_in,
                              void* d_out, int out_size, void* d_ws, size_t ws_size,
                              hipStream_t stream) {
    const float* x  = (const float*)d_in[0];
    const float* Wx = (const float*)d_in[1];
    const float* bx = (const float*)d_in[2];
    const float* Wh = (const float*)d_in[3];
    float* out = (float*)d_out;
    float* hws = (float*)d_ws;                               // 2 MB h pong
    int*   flags = (int*)((char*)d_ws + (3u << 20));         // 1 KB counters
    uint4* wfrag = (uint4*)((char*)d_ws + (4u << 20));       // 74 KB A-frags

    // h0 = zeros in d_out (even t: read out -> write ws; t=63 odd => final in out)
    hipMemsetAsync(d_out, 0, (size_t)524288 * sizeof(float), stream);
    hipMemsetAsync(flags, 0, 4 * 64 * sizeof(int), stream);
    hipLaunchKernelGGL(build_wfrag, dim3(72), dim3(64), 0, stream, Wx, Wh, wfrag);

    void* args[] = { (void*)&x, (void*)&bx, (void*)&wfrag,
                     (void*)&out, (void*)&hws, (void*)&flags };
    hipLaunchCooperativeKernel((const void*)convgru_persist,
                               dim3(64, 4), dim3(512), args, 0, stream);
}

// Round 2
// 706.611 us; speedup vs baseline: 4.2691x; 4.2691x over previous
//
#include <hip/hip_runtime.h>
#include <math.h>

// ConvGRU v10: persistent cooperative wavefront kernel, FENCE-FREE coherence.
// v9 post-mortem: agent acquire/release fences (buffer_inv/buffer_wbl2 per wave
// per step) cost ~45us/step. v10 removes ALL cache-wide maintenance:
//  - h stores/loads that cross blocks use per-access device-coherent ops
//    (__hip_atomic_* RELAXED AGENT -> global_*_dword sc0 sc1, L1/L2 bypass,
//    served at the device coherence point).  No fences anywhere.
//  - store->flag ordering: s_waitcnt vmcnt(0) (sc1 stores retire at coherence
//    point) then relaxed agent atomic add.
//  - hprev carried in REGISTERS (same lane computed it at t-1): zero loads.
//  - own-row h kept in LDS (hrow, 8KB): staging only round-trips the 2 halo
//    rows (ky=0,2) through L3; own row (ky=1) is an LDS read.
//  - spin confined to wave 0, lanes 0-2; other waves park on s_barrier.
// Same math as v8: MFMA implicit-GEMM, parity-split LDS copies, K-split x2.
// h ping-pongs d_out <-> d_ws; t=63 (odd) writes d_out.

typedef _Float16 half8 __attribute__((ext_vector_type(8)));
typedef float floatx16 __attribute__((ext_vector_type(16)));

#define RS 144                       // bytes per staged k-row (both copies)
#define CP1 (144 * RS)               // copy1 byte base (20736)
#define SCRDW (2 * 144 * RS / 4)     // scratch dword base (10368)
#define LDS_DW (SCRDW + 4 * 16 * 68) // + 4 tiles x 16 regs x 68-stride (14720 dw)

static __device__ __forceinline__ unsigned pack2(float a, float b) {
    _Float16 ha = (_Float16)a, hb = (_Float16)b;
    unsigned short ua = *(unsigned short*)&ha, ub = *(unsigned short*)&hb;
    return (unsigned)ua | ((unsigned)ub << 16);
}

// device-coherent (sc0 sc1) float load/store, no cache maintenance
static __device__ __forceinline__ float ld_dc(const float* p) {
    return __hip_atomic_load(p, __ATOMIC_RELAXED, __HIP_MEMORY_SCOPE_AGENT);
}
static __device__ __forceinline__ void st_dc(float* p, float v) {
    __hip_atomic_store(p, v, __ATOMIC_RELAXED, __HIP_MEMORY_SCOPE_AGENT);
}

// ---- pre-kernel: weights -> A-fragment layout (R6-verified, unchanged) ----
__global__ __launch_bounds__(64) void build_wfrag(
    const float* __restrict__ Wx, const float* __restrict__ Wh,
    uint4* __restrict__ wfrag)
{
    const int bid   = blockIdx.x;            // 0..71
    const int mtile = bid / 36, chunk = bid % 36;
    const int lane  = threadIdx.x;
    const int m     = lane & 31;
    const int grow  = (m < 16) ? (mtile * 16 + m) : (64 + mtile * 16 + (m - 16));
    unsigned short h[8];
    for (int j = 0; j < 8; ++j) {
        int k   = chunk * 16 + (lane >> 5) * 8 + j;
        int cin = k / 12, t12 = k - cin * 12;
        int p = t12 >> 1, o = t12 & 1;
        int ky = p >> 1, q = p & 1;
        int kx = q ? (2 + o) : o;            // q=1,o=1 -> phantom (w=0)
        float w = 0.0f;
        if (!(q && o)) {
            if (cin < 16) w = Wx[((size_t)grow * 16 + cin) * 9 + ky * 3 + kx];
            else          w = Wh[((size_t)grow * 32 + (cin - 16)) * 9 + ky * 3 + kx];
        }
        _Float16 hw = (_Float16)w;
        h[j] = *(unsigned short*)&hw;
    }
    uint4 o4;
    o4.x = (unsigned)h[0] | ((unsigned)h[1] << 16);
    o4.y = (unsigned)h[2] | ((unsigned)h[3] << 16);
    o4.z = (unsigned)h[4] | ((unsigned)h[5] << 16);
    o4.w = (unsigned)h[6] | ((unsigned)h[7] << 16);
    wfrag[(size_t)bid * 64 + lane] = o4;
}

__global__ __launch_bounds__(512, 2) void convgru_persist(
    const float* __restrict__ x, const float* __restrict__ bx,
    const uint4* __restrict__ wfrag,
    float* __restrict__ hO,      // d_out  (hsrc when t even, hdst when t odd)
    float* __restrict__ hW,      // ws     (hdst when t even)
    int* __restrict__ flags)     // [4][64] completion counters (+4 per step)
{
    __shared__ unsigned plds[LDS_DW];        // staging + scratch (58,880 B)
    __shared__ uint4    wlds[72 * 64];       // A-fragments      (73,728 B)
    __shared__ float    hrow[32 * 64];       // own-row h        ( 8,192 B)

    const int tx = threadIdx.x;
    const int y  = blockIdx.x;               // image row 0..63
    const int b  = blockIdx.y;               // batch 0..3
    const int lane  = tx & 63;
    const int wv    = tx >> 6;               // 0..7
    const int kh    = wv & 1;                // k-half: chunks 0-17 / 18-35
    const int mtile = (wv >> 1) & 1;
    const int ntile = wv >> 2;
    const int tile  = wv >> 1;               // 0..3 (shared by kh pair)
    const int xpx   = ntile * 32 + (lane & 31);
    const int half  = lane >> 5;
    const int lb_off = ((xpx & 1) ? (2 * xpx + 6) : (CP1 + 2 * xpx))
                       + half * (2 * RS);
    const char* lbase = (const char*)plds + lb_off;

    // one-time setup: wfrag -> LDS, copy0 halo dword = 0, hrow = h0 = 0
    #pragma unroll
    for (int i = 0; i < 9; ++i) wlds[i * 512 + tx] = wfrag[i * 512 + tx];
    if (tx < 144) plds[tx * 36 + 34] = 0u;
    ((float4*)hrow)[tx] = make_float4(0.f, 0.f, 0.f, 0.f);
    __syncthreads();

    int* const myflag = flags + b * 64 + y;

    // running h for this lane's 8 output cells (hprev without any load)
    float hcur[8];
    #pragma unroll
    for (int r = 0; r < 8; ++r) hcur[r] = 0.0f;

    #pragma unroll 1
    for (int t = 0; t < 64; ++t) {
        const float* hsrc = (t & 1) ? hW : hO;
        float*       hdst = (t & 1) ? hO : hW;

        // ---- (A) flag-independent x prefetch ----
        float4 xv0 = make_float4(0.f, 0.f, 0.f, 0.f), xv1 = xv0;
        {
            const int rr = tx >> 4, g = tx & 15;       // tasks 0..511 (cin<16)
            const int cin = rr / 3, ky = rr - cin * 3, ys = y + ky - 1;
            if ((unsigned)ys < 64u)
                xv0 = *(const float4*)(x + (((size_t)(b * 16 + cin) * 64 + t) * 4096)
                                         + ys * 64 + g * 4);
        }
        if (tx < 256) {
            const int task = 512 + tx;                 // tasks 512..767
            const int rr = task >> 4, g = task & 15;
            const int cin = rr / 3, ky = rr - cin * 3, ys = y + ky - 1;
            if ((unsigned)ys < 64u)
                xv1 = *(const float4*)(x + (((size_t)(b * 16 + cin) * 64 + t) * 4096)
                                         + ys * 64 + g * 4);
        }

        // ---- (D) x -> LDS (B-area free: step t-1 MFMA reads done pre-barrier) ----
        {
            const int rr = tx >> 4, g = tx & 15;
            float prev = __shfl_up(xv0.w, 1);
            if (g == 0) prev = 0.f;
            const int r36 = rr * 36;
            plds[r36 + 2 * g + 2] = pack2(xv0.x, xv0.y);
            plds[r36 + 2 * g + 3] = pack2(xv0.z, xv0.w);
            plds[CP1 / 4 + r36 + 2 * g]     = pack2(prev, xv0.x);
            plds[CP1 / 4 + r36 + 2 * g + 1] = pack2(xv0.y, xv0.z);
            if (g == 15) plds[CP1 / 4 + r36 + 32] = pack2(xv0.w, 0.f);
        }
        if (tx < 256) {
            const int task = 512 + tx;
            const int rr = task >> 4, g = task & 15;
            float prev = __shfl_up(xv1.w, 1);
            if (g == 0) prev = 0.f;
            const int r36 = rr * 36;
            plds[r36 + 2 * g + 2] = pack2(xv1.x, xv1.y);
            plds[r36 + 2 * g + 3] = pack2(xv1.z, xv1.w);
            plds[CP1 / 4 + r36 + 2 * g]     = pack2(prev, xv1.x);
            plds[CP1 / 4 + r36 + 2 * g + 1] = pack2(xv1.y, xv1.z);
            if (g == 15) plds[CP1 / 4 + r36 + 32] = pack2(xv1.w, 0.f);
        }

        // ---- (B) wait for neighbors' h(t-1): wave 0 spins, rest park ----
        if (t > 0) {
            if (wv == 0 && lane < 3) {
                const int yy = y + (int)lane - 1;
                if (0 <= yy && yy < 64) {
                    const int tgt = 4 * t;             // 4 kh0-waves per step
                    while (__hip_atomic_load(flags + b * 64 + yy, __ATOMIC_RELAXED,
                                             __HIP_MEMORY_SCOPE_AGENT) < tgt) { }
                }
            }
            __syncthreads();                           // release other waves
        }

        // ---- (C) h(t-1) -> LDS: tasks 768..2303 (cin 16..47) ----
        // ky==1 (own row): LDS hrow.  ky==0,2 (halo): device-coherent loads.
        #pragma unroll
        for (int j = 0; j < 3; ++j) {
            const int task = 768 + j * 512 + tx;
            const int rr = task >> 4, g = task & 15;
            const int cin = rr / 3, ky = rr - cin * 3, ys = y + ky - 1;
            float4 v = make_float4(0.f, 0.f, 0.f, 0.f);
            if (ky == 1) {
                v = *(const float4*)(hrow + (cin - 16) * 64 + g * 4);
            } else if ((unsigned)ys < 64u) {
                const float* p = hsrc + ((size_t)(b * 32 + (cin - 16)) * 4096)
                                      + ys * 64 + g * 4;
                v.x = ld_dc(p);     v.y = ld_dc(p + 1);
                v.z = ld_dc(p + 2); v.w = ld_dc(p + 3);
            }
            float prev = __shfl_up(v.w, 1);
            if (g == 0) prev = 0.f;
            const int r36 = rr * 36;
            plds[r36 + 2 * g + 2] = pack2(v.x, v.y);
            plds[r36 + 2 * g + 3] = pack2(v.z, v.w);
            plds[CP1 / 4 + r36 + 2 * g]     = pack2(prev, v.x);
            plds[CP1 / 4 + r36 + 2 * g + 1] = pack2(v.y, v.z);
            if (g == 15) plds[CP1 / 4 + r36 + 32] = pack2(v.w, 0.f);
        }
        __syncthreads();                               // stage-sync

        // ---- MFMA main loop (A-frags from LDS) ----
        floatx16 acc;
        #pragma unroll
        for (int i = 0; i < 16; ++i) acc[i] = 0.0f;
        const int c0 = kh * 18;
        #pragma unroll
        for (int j = 0; j < 18; ++j) {
            const int c = c0 + j;
            uint4 aw = wlds[(mtile * 36 + c) * 64 + lane];
            const int B0 = c * 4 * RS;
            unsigned d0 = *(const unsigned*)(lbase + B0);
            unsigned d1 = *(const unsigned*)(lbase + B0 + 4);
            unsigned e0 = *(const unsigned*)(lbase + B0 + RS);
            unsigned e1 = *(const unsigned*)(lbase + B0 + RS + 4);
            uint4 bf; bf.x = d0; bf.y = d1; bf.z = e0; bf.w = e1;
            union { uint4 u; half8 h; } ua, ub;
            ua.u = aw; ub.u = bf;
            acc = __builtin_amdgcn_mfma_f32_32x32x16_f16(ua.h, ub.h, acc, 0, 0, 0);
        }

        // ---- K-split reduction ----
        if (kh == 1) {
            #pragma unroll
            for (int r = 0; r < 16; ++r)
                plds[SCRDW + tile * 1088 + r * 68 + lane] = __float_as_uint(acc[r]);
        }
        __syncthreads();                               // reduce-sync

        if (kh == 0) {
            #pragma unroll
            for (int r = 0; r < 16; ++r)
                acc[r] += __uint_as_float(plds[SCRDW + tile * 1088 + r * 68 + lane]);

            // epilogue: gates + h update; write LDS hrow + device-coherent global
            #pragma unroll
            for (int r = 0; r < 8; ++r) {
                const int row = (r & 3) + 8 * (r >> 2) + 4 * half;
                const int oc  = mtile * 16 + row;
                const size_t a = (size_t)(b * 32 + oc) * 4096 + y * 64 + xpx;
                float zp = acc[r]     + bx[oc];
                float np = acc[r + 8] + bx[64 + oc];
                float z  = 1.0f / (1.0f + __expf(-zp));
                float e  = __expf(2.0f * np);
                float n  = 1.0f - 2.0f / (e + 1.0f);               // tanh
                float hn = (1.0f - z) * hcur[r] + z * n;
                hcur[r] = hn;
                hrow[oc * 64 + xpx] = hn;
                st_dc(hdst + a, hn);
            }
            // sc1 stores retire at the device coherence point -> vmcnt(0) is
            // a sufficient release for the flag add (no buffer_wbl2 needed)
            asm volatile("s_waitcnt vmcnt(0)" ::: "memory");
            if (lane == 0)
                __hip_atomic_fetch_add(myflag, 1, __ATOMIC_RELAXED,
                                       __HIP_MEMORY_SCOPE_AGENT);
        }
    }
}

extern "C" void kernel_launch(void* const* d_in, const int* in_sizes, int n_in,
                              void* d_out, int out_size, void* d_ws, size_t ws_size,
                              hipStream_t stream) {
    const float* x  = (const float*)d_in[0];
    const float* Wx = (const float*)d_in[1];
    const float* bx = (const float*)d_in[2];
    const float* Wh = (const float*)d_in[3];
    float* out = (float*)d_out;
    float* hws = (float*)d_ws;                               // 2 MB h pong
    int*   flags = (int*)((char*)d_ws + (3u << 20));         // 1 KB counters
    uint4* wfrag = (uint4*)((char*)d_ws + (4u << 20));       // 74 KB A-frags

    // h0 = zeros in d_out (even t: read out -> write ws; t=63 odd => final in out)
    hipMemsetAsync(d_out, 0, (size_t)524288 * sizeof(float), stream);
    hipMemsetAsync(flags, 0, 4 * 64 * sizeof(int), stream);
    hipLaunchKernelGGL(build_wfrag, dim3(72), dim3(64), 0, stream, Wx, Wh, wfrag);

    void* args[] = { (void*)&x, (void*)&bx, (void*)&wfrag,
                     (void*)&out, (void*)&hws, (void*)&flags };
    hipLaunchCooperativeKernel((const void*)convgru_persist,
                               dim3(64, 4), dim3(512), args, 0, stream);
}

// Round 3
// 466.144 us; speedup vs baseline: 6.4714x; 1.5159x over previous
//
#include <hip/hip_runtime.h>
#include <math.h>

// ConvGRU v11: persistent wavefront kernel; minimized coherent-op legs.
// v10 post-mortem: per-step critical path was ~6-8 serialized L2-bypass
// round-trips (scalar atomic halo loads the compiler won't batch, 2048
// scattered scalar sc1 stores, spin, add). v11:
//  - intermediate h layout = row-blocks (b,y,cin,x): block's output row is
//    contiguous 8KB -> dump = ONE global_store_dwordx4 sc0 sc1 per thread
//    (from LDS hrow), coalesced; drain is one vmcnt leg.
//  - halo stage = ONE asm block per thread issuing BOTH rows' dwordx4 loads
//    then a single vmcnt(0): one latency leg. Own row comes from LDS hrow.
//    Each thread owns exactly one ky=0 / ky=1 / ky=2 task (proof: ky_j =
//    (2j + (tx>>4)) mod 3, j=0..2 distinct); selection is branchless so
//    shfl_up stays wave-uniform.
//  - per-neighbor inbox slots inbox[b][y][2] (no sum-masking): lane0 polls
//    slot0 (from y-1), lane1 slot1 (from y+1); producer adds to the two
//    neighbors' opposite slots after the dump drains.
//  - t=63 (odd) reads pong and writes d_out in NCHW directly from registers;
//    d_out doubles as the raw ping buffer for t<63.
// Math unchanged from v8: MFMA implicit-GEMM, parity-split LDS copies,
// K-split x2 over 8 waves, hprev carried in registers.

typedef _Float16 half8 __attribute__((ext_vector_type(8)));
typedef float floatx16 __attribute__((ext_vector_type(16)));
typedef float floatx4 __attribute__((ext_vector_type(4)));

#define RS 144                       // bytes per staged k-row (both copies)
#define CP1 (144 * RS)               // copy1 byte base (20736)
#define SCRDW (2 * 144 * RS / 4)     // scratch dword base (10368)
#define LDS_DW (SCRDW + 4 * 16 * 68) // + 4 tiles x 16 regs x 68-stride (14720 dw)

static __device__ __forceinline__ unsigned pack2(float a, float b) {
    _Float16 ha = (_Float16)a, hb = (_Float16)b;
    unsigned short ua = *(unsigned short*)&ha, ub = *(unsigned short*)&hb;
    return (unsigned)ua | ((unsigned)ub << 16);
}

// device-coherent dwordx4 ops (sc0 sc1: L1/L2 bypass, served at device
// coherence point; no cache-wide maintenance).
static __device__ __forceinline__ void ld_dc4_2(const float* p0, const float* p1,
                                                floatx4& a, floatx4& b) {
    asm volatile("global_load_dwordx4 %0, %2, off sc0 sc1\n\t"
                 "global_load_dwordx4 %1, %3, off sc0 sc1\n\t"
                 "s_waitcnt vmcnt(0)"
                 : "=&v"(a), "=&v"(b) : "v"(p0), "v"(p1));
}
static __device__ __forceinline__ floatx4 ld_dc4(const float* p) {
    floatx4 a;
    asm volatile("global_load_dwordx4 %0, %1, off sc0 sc1\n\t"
                 "s_waitcnt vmcnt(0)"
                 : "=v"(a) : "v"(p));
    return a;
}
static __device__ __forceinline__ void st_dc4(float* p, floatx4 v) {
    asm volatile("global_store_dwordx4 %0, %1, off sc0 sc1"
                 :: "v"(p), "v"(v) : "memory");
}

// ---- pre-kernel: weights -> A-fragment layout (R6-verified, unchanged) ----
__global__ __launch_bounds__(64) void build_wfrag(
    const float* __restrict__ Wx, const float* __restrict__ Wh,
    uint4* __restrict__ wfrag)
{
    const int bid   = blockIdx.x;            // 0..71
    const int mtile = bid / 36, chunk = bid % 36;
    const int lane  = threadIdx.x;
    const int m     = lane & 31;
    const int grow  = (m < 16) ? (mtile * 16 + m) : (64 + mtile * 16 + (m - 16));
    unsigned short h[8];
    for (int j = 0; j < 8; ++j) {
        int k   = chunk * 16 + (lane >> 5) * 8 + j;
        int cin = k / 12, t12 = k - cin * 12;
        int p = t12 >> 1, o = t12 & 1;
        int ky = p >> 1, q = p & 1;
        int kx = q ? (2 + o) : o;            // q=1,o=1 -> phantom (w=0)
        float w = 0.0f;
        if (!(q && o)) {
            if (cin < 16) w = Wx[((size_t)grow * 16 + cin) * 9 + ky * 3 + kx];
            else          w = Wh[((size_t)grow * 32 + (cin - 16)) * 9 + ky * 3 + kx];
        }
        _Float16 hw = (_Float16)w;
        h[j] = *(unsigned short*)&hw;
    }
    uint4 o4;
    o4.x = (unsigned)h[0] | ((unsigned)h[1] << 16);
    o4.y = (unsigned)h[2] | ((unsigned)h[3] << 16);
    o4.z = (unsigned)h[4] | ((unsigned)h[5] << 16);
    o4.w = (unsigned)h[6] | ((unsigned)h[7] << 16);
    wfrag[(size_t)bid * 64 + lane] = o4;
}

__global__ __launch_bounds__(512, 2) void convgru_persist(
    const float* __restrict__ x, const float* __restrict__ bx,
    const uint4* __restrict__ wfrag,
    float* __restrict__ hbuf0,   // ping (aliases d_out, raw row-block layout)
    float* __restrict__ hbuf1,   // pong (ws)
    float* __restrict__ out,     // final NCHW (t=63 only)
    int* __restrict__ flags)     // inbox[b][y][2]: [0]=from y-1, [1]=from y+1
{
    __shared__ unsigned plds[LDS_DW];        // staging + scratch (58,880 B)
    __shared__ uint4    wlds[72 * 64];       // A-fragments      (73,728 B)
    __shared__ floatx4  hrow4[512];          // own-row h        ( 8,192 B)
    float* const hrow = (float*)hrow4;

    const int tx = threadIdx.x;
    const int y  = blockIdx.x;               // image row 0..63
    const int b  = blockIdx.y;               // batch 0..3
    const int lane  = tx & 63;
    const int wv    = tx >> 6;               // 0..7
    const int kh    = wv & 1;                // k-half: chunks 0-17 / 18-35
    const int mtile = (wv >> 1) & 1;
    const int ntile = wv >> 2;
    const int tile  = wv >> 1;               // 0..3 (shared by kh pair)
    const int xpx   = ntile * 32 + (lane & 31);
    const int half  = lane >> 5;
    const int lb_off = ((xpx & 1) ? (2 * xpx + 6) : (CP1 + 2 * xpx))
                       + half * (2 * RS);
    const char* lbase = (const char*)plds + lb_off;

    // one-time setup: wfrag -> LDS, copy0 halo dword = 0, hrow = h0 = 0
    #pragma unroll
    for (int i = 0; i < 9; ++i) wlds[i * 512 + tx] = wfrag[i * 512 + tx];
    if (tx < 144) plds[tx * 36 + 34] = 0u;
    hrow4[tx] = (floatx4)(0.f);
    __syncthreads();

    int* const inbox = flags + (b * 64 + y) * 2;

    // running h for this lane's 8 output cells (no hprev loads ever)
    float hcur[8];
    #pragma unroll
    for (int r = 0; r < 8; ++r) hcur[r] = 0.0f;

    #pragma unroll 1
    for (int t = 0; t < 64; ++t) {
        const float* hsrc = (t & 1) ? hbuf1 : hbuf0;   // row-block layout
        float*       hdst = (t & 1) ? hbuf0 : hbuf1;   // (t<63 only)

        // ---- (A) flag-independent x prefetch ----
        float4 xv0 = make_float4(0.f, 0.f, 0.f, 0.f), xv1 = xv0;
        {
            const int rr = tx >> 4, g = tx & 15;       // tasks 0..511 (cin<16)
            const int cin = rr / 3, ky = rr - cin * 3, ys = y + ky - 1;
            if ((unsigned)ys < 64u)
                xv0 = *(const float4*)(x + (((size_t)(b * 16 + cin) * 64 + t) * 4096)
                                         + ys * 64 + g * 4);
        }
        if (tx < 256) {
            const int task = 512 + tx;                 // tasks 512..767
            const int rr = task >> 4, g = task & 15;
            const int cin = rr / 3, ky = rr - cin * 3, ys = y + ky - 1;
            if ((unsigned)ys < 64u)
                xv1 = *(const float4*)(x + (((size_t)(b * 16 + cin) * 64 + t) * 4096)
                                         + ys * 64 + g * 4);
        }

        // ---- (D) x -> LDS (B-area free: step t-1 MFMA reads pre-barrier) ----
        {
            const int rr = tx >> 4, g = tx & 15;
            float prev = __shfl_up(xv0.w, 1);
            if (g == 0) prev = 0.f;
            const int r36 = rr * 36;
            plds[r36 + 2 * g + 2] = pack2(xv0.x, xv0.y);
            plds[r36 + 2 * g + 3] = pack2(xv0.z, xv0.w);
            plds[CP1 / 4 + r36 + 2 * g]     = pack2(prev, xv0.x);
            plds[CP1 / 4 + r36 + 2 * g + 1] = pack2(xv0.y, xv0.z);
            if (g == 15) plds[CP1 / 4 + r36 + 32] = pack2(xv0.w, 0.f);
        }
        if (tx < 256) {
            const int task = 512 + tx;
            const int rr = task >> 4, g = task & 15;
            float prev = __shfl_up(xv1.w, 1);
            if (g == 0) prev = 0.f;
            const int r36 = rr * 36;
            plds[r36 + 2 * g + 2] = pack2(xv1.x, xv1.y);
            plds[r36 + 2 * g + 3] = pack2(xv1.z, xv1.w);
            plds[CP1 / 4 + r36 + 2 * g]     = pack2(prev, xv1.x);
            plds[CP1 / 4 + r36 + 2 * g + 1] = pack2(xv1.y, xv1.z);
            if (g == 15) plds[CP1 / 4 + r36 + 32] = pack2(xv1.w, 0.f);
        }

        // ---- (B) wait for neighbors' h(t-1): 2 lanes poll own inbox ----
        if (t > 0) {
            if (wv == 0 && lane < 2) {
                const bool valid = lane ? (y < 63) : (y > 0);
                if (valid) {
                    while (__hip_atomic_load(inbox + lane, __ATOMIC_RELAXED,
                                             __HIP_MEMORY_SCOPE_AGENT) < t) { }
                }
            }
            __syncthreads();
        }

        // ---- (C) h(t-1) -> LDS: tasks 768..2303 (cin 16..47) ----
        // thread tx, task j: rr = 48 + 32j + s (s = tx>>4), ky = (2j+s)%3.
        // jm (ky=0, row y-1) = s%3; j1 (ky=1, own row, LDS) = (2-2s)%3;
        // jp (ky=2, row y+1) = remaining. One dual coherent load, one LDS read.
        {
            const int g = tx & 15;
            const int s = tx >> 4;                     // 0..31
            const int q = s % 3;
            const int jm = q;
            const int j1 = (q == 0) ? 2 : (q == 1) ? 0 : 1;
            const int jp = 3 - jm - j1;
            const int rr_m = 48 + 32 * jm + s;
            const int rr_1 = 48 + 32 * j1 + s;
            const int rr_p = 48 + 32 * jp + s;
            const int col = g * 4;
            floatx4 vm = (floatx4)(0.f), vp = (floatx4)(0.f);
            const float* pm = hsrc + ((size_t)(b * 64 + (y - 1)) * 2048)
                                   + (rr_m / 3 - 16) * 64 + col;
            const float* pp = hsrc + ((size_t)(b * 64 + (y + 1)) * 2048)
                                   + (rr_p / 3 - 16) * 64 + col;
            if (y == 0)       vp = ld_dc4(pp);
            else if (y == 63) vm = ld_dc4(pm);
            else              ld_dc4_2(pm, pp, vm, vp);
            const floatx4 vo = *(const floatx4*)(hrow + (rr_1 / 3 - 16) * 64 + col);
            #pragma unroll
            for (int j = 0; j < 3; ++j) {
                const int rr = 48 + 32 * j + s;
                floatx4 v = (j == jm) ? vm : ((j == j1) ? vo : vp);
                float prev = __shfl_up(v[3], 1);
                if (g == 0) prev = 0.f;
                const int r36 = rr * 36;
                plds[r36 + 2 * g + 2] = pack2(v[0], v[1]);
                plds[r36 + 2 * g + 3] = pack2(v[2], v[3]);
                plds[CP1 / 4 + r36 + 2 * g]     = pack2(prev, v[0]);
                plds[CP1 / 4 + r36 + 2 * g + 1] = pack2(v[1], v[2]);
                if (g == 15) plds[CP1 / 4 + r36 + 32] = pack2(v[3], 0.f);
            }
        }
        __syncthreads();                               // stage-sync

        // ---- MFMA main loop (A-frags from LDS) ----
        floatx16 acc;
        #pragma unroll
        for (int i = 0; i < 16; ++i) acc[i] = 0.0f;
        const int c0 = kh * 18;
        #pragma unroll
        for (int j = 0; j < 18; ++j) {
            const int c = c0 + j;
            uint4 aw = wlds[(mtile * 36 + c) * 64 + lane];
            const int B0 = c * 4 * RS;
            unsigned d0 = *(const unsigned*)(lbase + B0);
            unsigned d1 = *(const unsigned*)(lbase + B0 + 4);
            unsigned e0 = *(const unsigned*)(lbase + B0 + RS);
            unsigned e1 = *(const unsigned*)(lbase + B0 + RS + 4);
            uint4 bf; bf.x = d0; bf.y = d1; bf.z = e0; bf.w = e1;
            union { uint4 u; half8 h; } ua, ub;
            ua.u = aw; ub.u = bf;
            acc = __builtin_amdgcn_mfma_f32_32x32x16_f16(ua.h, ub.h, acc, 0, 0, 0);
        }

        // ---- K-split reduction ----
        if (kh == 1) {
            #pragma unroll
            for (int r = 0; r < 16; ++r)
                plds[SCRDW + tile * 1088 + r * 68 + lane] = __float_as_uint(acc[r]);
        }
        __syncthreads();                               // reduce-sync

        if (kh == 0) {
            #pragma unroll
            for (int r = 0; r < 16; ++r)
                acc[r] += __uint_as_float(plds[SCRDW + tile * 1088 + r * 68 + lane]);

            // epilogue: gates + h update -> registers + LDS hrow
            #pragma unroll
            for (int r = 0; r < 8; ++r) {
                const int row = (r & 3) + 8 * (r >> 2) + 4 * half;
                const int oc  = mtile * 16 + row;
                float zp = acc[r]     + bx[oc];
                float np = acc[r + 8] + bx[64 + oc];
                float z  = 1.0f / (1.0f + __expf(-zp));
                float e  = __expf(2.0f * np);
                float n  = 1.0f - 2.0f / (e + 1.0f);               // tanh
                float hn = (1.0f - z) * hcur[r] + z * n;
                hcur[r] = hn;
                if (t == 63)
                    out[(size_t)(b * 32 + oc) * 4096 + y * 64 + xpx] = hn;
                else
                    hrow[oc * 64 + xpx] = hn;
            }
        }

        // ---- publish h(t): coalesced x4 dump from hrow + inbox adds ----
        if (t < 63) {
            __syncthreads();                           // hrow ready
            st_dc4(hdst + ((size_t)(b * 64 + y) * 2048) + tx * 4, hrow4[tx]);
            asm volatile("s_waitcnt vmcnt(0)" ::: "memory");
            __syncthreads();                           // all stores drained
            if (wv == 0 && lane < 2) {
                const int yy = lane ? (y + 1) : (y - 1);
                if (0 <= yy && yy < 64)
                    __hip_atomic_fetch_add(flags + (b * 64 + yy) * 2 + (lane ^ 1),
                                           1, __ATOMIC_RELAXED,
                                           __HIP_MEMORY_SCOPE_AGENT);
            }
        }
    }
}

extern "C" void kernel_launch(void* const* d_in, const int* in_sizes, int n_in,
                              void* d_out, int out_size, void* d_ws, size_t ws_size,
                              hipStream_t stream) {
    const float* x  = (const float*)d_in[0];
    const float* Wx = (const float*)d_in[1];
    const float* bx = (const float*)d_in[2];
    const float* Wh = (const float*)d_in[3];
    float* out   = (float*)d_out;
    float* hbuf0 = (float*)d_out;                            // ping (raw scratch)
    float* hbuf1 = (float*)d_ws;                             // pong (2 MB)
    uint4* wfrag = (uint4*)((char*)d_ws + (2u << 20));       // 74 KB A-frags
    int*   flags = (int*)((char*)d_ws + (2u << 20) + (80u << 10)); // 2 KB inbox

    // h0 = zeros in hbuf0 (= d_out); t=63 overwrites d_out with NCHW result.
    hipMemsetAsync(d_out, 0, (size_t)524288 * sizeof(float), stream);
    hipMemsetAsync(flags, 0, 4 * 64 * 2 * sizeof(int), stream);
    hipLaunchKernelGGL(build_wfrag, dim3(72), dim3(64), 0, stream, Wx, Wh, wfrag);

    void* args[] = { (void*)&x, (void*)&bx, (void*)&wfrag,
                     (void*)&hbuf0, (void*)&hbuf1, (void*)&out, (void*)&flags };
    hipLaunchCooperativeKernel((const void*)convgru_persist,
                               dim3(64, 4), dim3(512), args, 0, stream);
}